// Round 10
// baseline (155.115 us; speedup 1.0000x reference)
//
#include <hip/hip_runtime.h>
#include <math.h>

#define BB 32
#define SS 2048
#define HH 128
#define AA 8

typedef _Float16 h2 __attribute__((ext_vector_type(2)));
typedef _Float16 h8 __attribute__((ext_vector_type(8)));
typedef _Float16 f16x8 __attribute__((ext_vector_type(8)));
typedef float f32x4 __attribute__((ext_vector_type(4)));

// ws layout:
//   bfrag:  [12][64] uint4 (12288 B, in the first 16 KB slot) — u in MFMA
//           B-fragment layout: bfrag[kk][lane] = 8 f16, element j = B[k][c],
//           k = kk*32 + (lane>>4)*8 + j (k = w*128 + d), c = lane&15 (0 if c>=8)
//   E:      [B][A][S]     524288 floats (masked exp(score), unnormalized)
//   Zpart:  [B][A][32]    8192
//   pools:  [B][32][A][H] 1048576 (unnormalized partial context sums)

__global__ __launch_bounds__(256) void prep_kernel(const float* __restrict__ embed,
                                                   const float* __restrict__ proj,
                                                   uint4* __restrict__ bfrag) {
    __shared__ float u[HH * 24];   // u[d*24 + a*3 + w]
    int t = threadIdx.x;
    for (int o = t; o < HH * 24; o += 256) {
        int d = o / 24, col = o % 24, a = col / 3, w = col % 3;
        const float* P  = proj + ((size_t)a * HH + d) * HH;
        const float* Ew = embed + a * 3 * HH + w;
        float s = 0.f;
        for (int h = 0; h < HH; ++h) s += P[h] * Ew[h * 3];
        u[o] = s;
    }
    __syncthreads();
    for (int f = t; f < 12 * 64; f += 256) {
        int kk = f >> 6, l = f & 63;
        int c = l & 15, kb = (l >> 4) * 8;
        f16x8 v;
        #pragma unroll
        for (int j = 0; j < 8; ++j) {
            int k = kk * 32 + kb + j;
            int w = k >> 7, d = k & 127;
            v[j] = (c < 8) ? (_Float16)u[d * 24 + c * 3 + w] : (_Float16)0.f;
        }
        bfrag[f] = __builtin_bit_cast(uint4, v);
    }
}

// Per (b, 64-s tile): scores via MFMA (A = f16 doc windows from LDS,
// B = prepacked u fragments) -> E = mask*exp(score), Zpart, unnormalized
// pooled context sums. Max-free exp is safe: |score| < ~0.2.
__global__ __launch_bounds__(256, 4) void tile_kernel(const float* __restrict__ doc,
                                                      const int* __restrict__ mask,
                                                      const uint4* __restrict__ bfrag,
                                                      float* __restrict__ E,
                                                      float* __restrict__ Zpart,
                                                      float* __restrict__ pools) {
    // dt [66][72] h2 (19008 B) + etile [64][8] f32 (2048) + zred [8][8] (256)
    __shared__ __align__(16) unsigned char smraw[21312];
    h2*    dt    = (h2*)smraw;
    float* etile = (float*)(smraw + 19008);
    float* zred  = (float*)(smraw + 19008 + 2048);

    int t = threadIdx.x;
    int lane = t & 63, wave = t >> 6;
    int tile = blockIdx.x;   // 0..31, 64 s each
    int b = blockIdx.y;
    int s0 = tile * 64;

    // ---- stage rows s0-1 .. s0+64 as f16 (zero outside [0,S)), stride 72 h2 ----
    for (int idx = t; idx < 66 * 16; idx += 256) {
        int row = idx >> 4, c = idx & 15;   // c: 8-float chunk
        int srow = s0 - 1 + row;
        h8 hv = {0, 0, 0, 0, 0, 0, 0, 0};
        if (srow >= 0 && srow < SS) {
            const float4* src = (const float4*)(doc + ((size_t)b * SS + srow) * HH + c * 8);
            float4 v0 = src[0], v1 = src[1];
            hv[0] = (_Float16)v0.x; hv[1] = (_Float16)v0.y;
            hv[2] = (_Float16)v0.z; hv[3] = (_Float16)v0.w;
            hv[4] = (_Float16)v1.x; hv[5] = (_Float16)v1.y;
            hv[6] = (_Float16)v1.z; hv[7] = (_Float16)v1.w;
        }
        *(h8*)(dt + row * 72 + c * 4) = hv;
    }

    // ---- B fragments: 12 x 16B per lane (L2-hot; same for all blocks) ----
    f16x8 bf[12];
    #pragma unroll
    for (int kk = 0; kk < 12; ++kk)
        bf[kk] = __builtin_bit_cast(f16x8, bfrag[kk * 64 + lane]);
    __syncthreads();   // dt ready

    // ---- scores: wave covers s rows wave*16 .. wave*16+15 ----
    // A[s][k]: k = w*128 + d -> dt row (s_local + w), cols d. Lane layout:
    // row = lane&15, k-base = (lane>>4)*8 within each 32-wide K-step.
    f32x4 acc = {0.f, 0.f, 0.f, 0.f};
    #pragma unroll
    for (int kk = 0; kk < 12; ++kk) {
        int w = kk >> 2;
        int row = wave * 16 + (lane & 15) + w;
        int colh2 = (kk & 3) * 16 + (lane >> 4) * 4;
        f16x8 af = *(const f16x8*)(dt + row * 72 + colh2);
        acc = __builtin_amdgcn_mfma_f32_16x16x32_f16(af, bf[kk], acc, 0, 0, 0);
    }

    // D layout: col = lane&15 (aspect), row = (lane>>4)*4 + reg (s within 16-block)
    const int* mrow = mask + (size_t)b * SS + s0;
    {
        int a = lane & 15;
        int rbase = wave * 16 + (lane >> 4) * 4;
        if (a < 8) {
            #pragma unroll
            for (int jj = 0; jj < 4; ++jj) {
                int sl2 = rbase + jj;
                float e = mrow[sl2] ? __expf(acc[jj]) : 0.f;
                E[((size_t)(b * AA + a)) * SS + s0 + sl2] = e;
                etile[sl2 * 8 + a] = e;
            }
        }
    }
    __syncthreads();
    if (t < 64) {
        int a = t & 7, g = t >> 3;
        float p = 0.f;
        #pragma unroll
        for (int k = 0; k < 8; ++k) p += etile[(g * 8 + k) * 8 + a];
        zred[g * 8 + a] = p;
    }
    __syncthreads();
    if (t < 8) {
        float z = 0.f;
        #pragma unroll
        for (int g = 0; g < 8; ++g) z += zred[g * 8 + t];
        Zpart[((size_t)(b * AA + t)) * 32 + tile] = z;
    }

    // ---- pool from f16 LDS: thread (dq, sub); d = dq*4, s = sub*8 + i ----
    int dq = t & 31, sub = t >> 5;
    float4 pacc[8];
    #pragma unroll
    for (int a = 0; a < 8; ++a) pacc[a] = make_float4(0.f, 0.f, 0.f, 0.f);
    for (int i = 0; i < 8; ++i) {
        int row = 1 + sub * 8 + i;
        uint2 X = *(const uint2*)(dt + row * 72 + dq * 2);
        h2 lo = __builtin_bit_cast(h2, X.x), hi = __builtin_bit_cast(h2, X.y);
        float x0 = (float)lo[0], x1 = (float)lo[1];
        float x2 = (float)hi[0], x3 = (float)hi[1];
        #pragma unroll
        for (int a = 0; a < 8; ++a) {
            float w = etile[(sub * 8 + i) * 8 + a];
            pacc[a].x += w * x0; pacc[a].y += w * x1;
            pacc[a].z += w * x2; pacc[a].w += w * x3;
        }
    }
    // pair-reduce subs 2k (lanes<32) + 2k+1 (lanes>=32) within each wave
    #pragma unroll
    for (int a = 0; a < 8; ++a) {
        pacc[a].x += __shfl_xor(pacc[a].x, 32);
        pacc[a].y += __shfl_xor(pacc[a].y, 32);
        pacc[a].z += __shfl_xor(pacc[a].z, 32);
        pacc[a].w += __shfl_xor(pacc[a].w, 32);
    }
    __syncthreads();   // all dt reads done -> reuse as cs2
    float* cs2 = (float*)smraw;   // [4 wave][8 a][128 d] = 16384 B < 19008 B
    if ((t & 63) < 32) {
        #pragma unroll
        for (int a = 0; a < 8; ++a)
            *(float4*)(cs2 + (wave * 8 + a) * 128 + dq * 4) = pacc[a];
    }
    __syncthreads();
    for (int oi = t; oi < 1024; oi += 256) {
        int a = oi >> 7, d = oi & 127;
        float v = (cs2[(0 * 8 + a) * 128 + d] + cs2[(1 * 8 + a) * 128 + d]) +
                  (cs2[(2 * 8 + a) * 128 + d] + cs2[(3 * 8 + a) * 128 + d]);
        pools[(((size_t)(b * 32 + tile)) * AA + a) * HH + d] = v;
    }
}

// Per (b, chunk): invZ from Zpart; attn = E*invZ; 32-h slice of rep.
__global__ __launch_bounds__(256) void finalize_kernel(const float* __restrict__ E,
                                                       const float* __restrict__ Zpart,
                                                       const float* __restrict__ pools,
                                                       const float* __restrict__ proj,
                                                       float* __restrict__ attn,
                                                       float* __restrict__ rep) {
    __shared__ float zbuf[256];
    __shared__ float invZ[8];
    __shared__ float ctxp[2][128];
    __shared__ float ctx[128];
    __shared__ float seg[8][32];
    int t = threadIdx.x;
    int ck = blockIdx.x;     // 0..31
    int b = blockIdx.y;
    int a_rep = ck & 7, hq = ck >> 3;

    zbuf[t] = Zpart[((size_t)(b * AA + (t >> 5))) * 32 + (t & 31)];
    __syncthreads();
    if (t < 8) {
        float z = 0.f;
        #pragma unroll
        for (int k = 0; k < 32; ++k) z += zbuf[t * 32 + k];
        invZ[t] = 1.0f / z;
    }
    __syncthreads();

    for (int oi = t; oi < 512; oi += 256) {
        int a = oi >> 6, s = oi & 63;
        size_t idx = ((size_t)(b * AA + a)) * SS + ck * 64 + s;
        attn[idx] = E[idx] * invZ[a];
    }

    {
        int d = t & 127, half = t >> 7;
        float v = 0.f;
        for (int c = half * 16; c < half * 16 + 16; ++c)
            v += pools[(((size_t)(b * 32 + c)) * AA + a_rep) * HH + d];
        ctxp[half][d] = v;
    }
    __syncthreads();
    if (t < 128) ctx[t] = (ctxp[0][t] + ctxp[1][t]) * invZ[a_rep];
    __syncthreads();

    {
        int h = hq * 32 + (t & 31), sg = t >> 5;
        float v = 0.f;
        for (int d = sg * 16; d < sg * 16 + 16; ++d)
            v += ctx[d] * proj[((size_t)a_rep * HH + d) * HH + h];
        seg[sg][t & 31] = v;
    }
    __syncthreads();
    if (t < 32) {
        float v = 0.f;
        #pragma unroll
        for (int sg = 0; sg < 8; ++sg) v += seg[sg][t];
        rep[((size_t)(b * AA + a_rep)) * HH + hq * 32 + t] = v;
    }
}

extern "C" void kernel_launch(void* const* d_in, const int* in_sizes, int n_in,
                              void* d_out, int out_size, void* d_ws, size_t ws_size,
                              hipStream_t stream) {
    const float* doc   = (const float*)d_in[0];   // [32][2048][128]
    const int*   mask  = (const int*)d_in[1];     // [32][2048]
    const float* embed = (const float*)d_in[2];   // [8][384]
    const float* proj  = (const float*)d_in[3];   // [8][128][128]

    float* out  = (float*)d_out;
    float* attn = out;                             // [32][8][2048]
    float* rep  = out + (size_t)BB * AA * SS;      // [32][8][128]

    uint4* bfrag = (uint4*)d_ws;                   // 12288 B of the 16 KB slot
    float* E     = (float*)d_ws + 4096;
    float* Zp    = E + (size_t)BB * AA * SS;
    float* pools = Zp + (size_t)BB * AA * 32;

    prep_kernel<<<1, 256, 0, stream>>>(embed, proj, bfrag);
    tile_kernel<<<dim3(32, 32), 256, 0, stream>>>(doc, mask, bfrag, E, Zp, pools);
    finalize_kernel<<<dim3(32, 32), 256, 0, stream>>>(E, Zp, pools, proj, attn, rep);
}

// Round 11
// 28.349 us; speedup vs baseline: 5.4716x; 5.4716x over previous
//
#include <hip/hip_runtime.h>
#include <math.h>

#define BB 32
#define SS 2048
#define HH 128
#define AA 8

typedef _Float16 h2 __attribute__((ext_vector_type(2)));
typedef _Float16 h8 __attribute__((ext_vector_type(8)));
typedef _Float16 f16x8 __attribute__((ext_vector_type(8)));
typedef float f32x4 __attribute__((ext_vector_type(4)));

// ws layout:
//   bfrag:  [12][64] uint4 (12288 B, in the first 16 KB slot) — u in MFMA
//           B-fragment layout: bfrag[kk][lane] = 8 f16, element j = B[k][c],
//           k = kk*32 + (lane>>4)*8 + j (k = w*128 + d), c = lane&15 (0 if c>=8)
//   E:      [B][A][S]     524288 floats (masked exp(score), unnormalized)
//   Zpart:  [B][A][32]    8192
//   pools:  [B][32][A][H] 1048576 (unnormalized partial context sums)

// 8 blocks x 128 threads (latency-parallel; R10's single-block version was a
// 133 µs serial-latency disaster). Block a: u_a[d][w] then the bfrag entries
// for lanes with c==a (real) and c==a+8 (zeros).
__global__ __launch_bounds__(128) void prep_kernel(const float* __restrict__ embed,
                                                   const float* __restrict__ proj,
                                                   uint4* __restrict__ bfrag) {
    __shared__ float ua[HH][3];   // u for this aspect: [d][w]
    int a = blockIdx.x;           // 0..7
    int d = threadIdx.x;          // 0..127
    const float* P = proj + ((size_t)a * HH + d) * HH;  // aspProj[a][d][:]
    const float* E = embed + a * (3 * HH);              // embedR[a][h][w] = E[h*3+w]
    float a0 = 0.f, a1 = 0.f, a2 = 0.f;
    for (int h = 0; h < HH; ++h) {
        float x = P[h];
        a0 += x * E[h * 3 + 0];   // E loads wave-uniform -> scalar cache
        a1 += x * E[h * 3 + 1];
        a2 += x * E[h * 3 + 2];
    }
    ua[d][0] = a0; ua[d][1] = a1; ua[d][2] = a2;
    __syncthreads();

    // 96 fragment entries for this block: i = kk*8 + e; e<4 -> lane q*16+a
    // (real), e>=4 -> lane (e-4)*16 + a + 8 (zero pad).
    for (int i = d; i < 96; i += 128) {
        int kk = i >> 3, e = i & 7;
        f16x8 v = {0, 0, 0, 0, 0, 0, 0, 0};
        int lane;
        if (e < 4) {
            int q = e;
            lane = q * 16 + a;
            #pragma unroll
            for (int j = 0; j < 8; ++j) {
                int k = kk * 32 + q * 8 + j;
                int w = k >> 7, dd = k & 127;
                v[j] = (_Float16)ua[dd][w];
            }
        } else {
            lane = (e - 4) * 16 + a + 8;   // zero columns 8..15
        }
        bfrag[kk * 64 + lane] = __builtin_bit_cast(uint4, v);
    }
}

// Per (b, 64-s tile): scores via MFMA (A = f16 doc windows from LDS,
// B = prepacked u fragments) -> E = mask*exp(score), Zpart, unnormalized
// pooled context sums. Max-free exp is safe: |score| < ~0.2.
__global__ __launch_bounds__(256, 4) void tile_kernel(const float* __restrict__ doc,
                                                      const int* __restrict__ mask,
                                                      const uint4* __restrict__ bfrag,
                                                      float* __restrict__ E,
                                                      float* __restrict__ Zpart,
                                                      float* __restrict__ pools) {
    // dt [66][72] h2 (19008 B) + etile [64][8] f32 (2048) + zred [8][8] (256)
    __shared__ __align__(16) unsigned char smraw[21312];
    h2*    dt    = (h2*)smraw;
    float* etile = (float*)(smraw + 19008);
    float* zred  = (float*)(smraw + 19008 + 2048);

    int t = threadIdx.x;
    int lane = t & 63, wave = t >> 6;
    int tile = blockIdx.x;   // 0..31, 64 s each
    int b = blockIdx.y;
    int s0 = tile * 64;

    // ---- stage rows s0-1 .. s0+64 as f16 (zero outside [0,S)), stride 72 h2 ----
    for (int idx = t; idx < 66 * 16; idx += 256) {
        int row = idx >> 4, c = idx & 15;   // c: 8-float chunk
        int srow = s0 - 1 + row;
        h8 hv = {0, 0, 0, 0, 0, 0, 0, 0};
        if (srow >= 0 && srow < SS) {
            const float4* src = (const float4*)(doc + ((size_t)b * SS + srow) * HH + c * 8);
            float4 v0 = src[0], v1 = src[1];
            hv[0] = (_Float16)v0.x; hv[1] = (_Float16)v0.y;
            hv[2] = (_Float16)v0.z; hv[3] = (_Float16)v0.w;
            hv[4] = (_Float16)v1.x; hv[5] = (_Float16)v1.y;
            hv[6] = (_Float16)v1.z; hv[7] = (_Float16)v1.w;
        }
        *(h8*)(dt + row * 72 + c * 4) = hv;
    }

    // ---- B fragments: 12 x 16B per lane (L2-hot; same for all blocks) ----
    f16x8 bf[12];
    #pragma unroll
    for (int kk = 0; kk < 12; ++kk)
        bf[kk] = __builtin_bit_cast(f16x8, bfrag[kk * 64 + lane]);
    __syncthreads();   // dt ready

    // ---- scores: wave covers s rows wave*16 .. wave*16+15 ----
    f32x4 acc = {0.f, 0.f, 0.f, 0.f};
    #pragma unroll
    for (int kk = 0; kk < 12; ++kk) {
        int w = kk >> 2;
        int row = wave * 16 + (lane & 15) + w;
        int colh2 = (kk & 3) * 16 + (lane >> 4) * 4;
        f16x8 af = *(const f16x8*)(dt + row * 72 + colh2);
        acc = __builtin_amdgcn_mfma_f32_16x16x32_f16(af, bf[kk], acc, 0, 0, 0);
    }

    // D layout: col = lane&15 (aspect), row = (lane>>4)*4 + reg (s within 16-block)
    const int* mrow = mask + (size_t)b * SS + s0;
    {
        int a = lane & 15;
        int rbase = wave * 16 + (lane >> 4) * 4;
        if (a < 8) {
            #pragma unroll
            for (int jj = 0; jj < 4; ++jj) {
                int sl2 = rbase + jj;
                float e = mrow[sl2] ? __expf(acc[jj]) : 0.f;
                E[((size_t)(b * AA + a)) * SS + s0 + sl2] = e;
                etile[sl2 * 8 + a] = e;
            }
        }
    }
    __syncthreads();
    if (t < 64) {
        int a = t & 7, g = t >> 3;
        float p = 0.f;
        #pragma unroll
        for (int k = 0; k < 8; ++k) p += etile[(g * 8 + k) * 8 + a];
        zred[g * 8 + a] = p;
    }
    __syncthreads();
    if (t < 8) {
        float z = 0.f;
        #pragma unroll
        for (int g = 0; g < 8; ++g) z += zred[g * 8 + t];
        Zpart[((size_t)(b * AA + t)) * 32 + tile] = z;
    }

    // ---- pool from f16 LDS: thread (dq, sub); d = dq*4, s = sub*8 + i ----
    int dq = t & 31, sub = t >> 5;
    float4 pacc[8];
    #pragma unroll
    for (int a = 0; a < 8; ++a) pacc[a] = make_float4(0.f, 0.f, 0.f, 0.f);
    for (int i = 0; i < 8; ++i) {
        int row = 1 + sub * 8 + i;
        uint2 X = *(const uint2*)(dt + row * 72 + dq * 2);
        h2 lo = __builtin_bit_cast(h2, X.x), hi = __builtin_bit_cast(h2, X.y);
        float x0 = (float)lo[0], x1 = (float)lo[1];
        float x2 = (float)hi[0], x3 = (float)hi[1];
        #pragma unroll
        for (int a = 0; a < 8; ++a) {
            float w = etile[(sub * 8 + i) * 8 + a];
            pacc[a].x += w * x0; pacc[a].y += w * x1;
            pacc[a].z += w * x2; pacc[a].w += w * x3;
        }
    }
    // pair-reduce subs 2k (lanes<32) + 2k+1 (lanes>=32) within each wave
    #pragma unroll
    for (int a = 0; a < 8; ++a) {
        pacc[a].x += __shfl_xor(pacc[a].x, 32);
        pacc[a].y += __shfl_xor(pacc[a].y, 32);
        pacc[a].z += __shfl_xor(pacc[a].z, 32);
        pacc[a].w += __shfl_xor(pacc[a].w, 32);
    }
    __syncthreads();   // all dt reads done -> reuse as cs2
    float* cs2 = (float*)smraw;   // [4 wave][8 a][128 d] = 16384 B < 19008 B
    if ((t & 63) < 32) {
        #pragma unroll
        for (int a = 0; a < 8; ++a)
            *(float4*)(cs2 + (wave * 8 + a) * 128 + dq * 4) = pacc[a];
    }
    __syncthreads();
    for (int oi = t; oi < 1024; oi += 256) {
        int a = oi >> 7, d = oi & 127;
        float v = (cs2[(0 * 8 + a) * 128 + d] + cs2[(1 * 8 + a) * 128 + d]) +
                  (cs2[(2 * 8 + a) * 128 + d] + cs2[(3 * 8 + a) * 128 + d]);
        pools[(((size_t)(b * 32 + tile)) * AA + a) * HH + d] = v;
    }
}

// Per (b, chunk): invZ from Zpart; attn = E*invZ; 32-h slice of rep.
__global__ __launch_bounds__(256) void finalize_kernel(const float* __restrict__ E,
                                                       const float* __restrict__ Zpart,
                                                       const float* __restrict__ pools,
                                                       const float* __restrict__ proj,
                                                       float* __restrict__ attn,
                                                       float* __restrict__ rep) {
    __shared__ float zbuf[256];
    __shared__ float invZ[8];
    __shared__ float ctxp[2][128];
    __shared__ float ctx[128];
    __shared__ float seg[8][32];
    int t = threadIdx.x;
    int ck = blockIdx.x;     // 0..31
    int b = blockIdx.y;
    int a_rep = ck & 7, hq = ck >> 3;

    zbuf[t] = Zpart[((size_t)(b * AA + (t >> 5))) * 32 + (t & 31)];
    __syncthreads();
    if (t < 8) {
        float z = 0.f;
        #pragma unroll
        for (int k = 0; k < 32; ++k) z += zbuf[t * 32 + k];
        invZ[t] = 1.0f / z;
    }
    __syncthreads();

    for (int oi = t; oi < 512; oi += 256) {
        int a = oi >> 6, s = oi & 63;
        size_t idx = ((size_t)(b * AA + a)) * SS + ck * 64 + s;
        attn[idx] = E[idx] * invZ[a];
    }

    {
        int d = t & 127, half = t >> 7;
        float v = 0.f;
        for (int c = half * 16; c < half * 16 + 16; ++c)
            v += pools[(((size_t)(b * 32 + c)) * AA + a_rep) * HH + d];
        ctxp[half][d] = v;
    }
    __syncthreads();
    if (t < 128) ctx[t] = (ctxp[0][t] + ctxp[1][t]) * invZ[a_rep];
    __syncthreads();

    {
        int h = hq * 32 + (t & 31), sg = t >> 5;
        float v = 0.f;
        for (int d = sg * 16; d < sg * 16 + 16; ++d)
            v += ctx[d] * proj[((size_t)a_rep * HH + d) * HH + h];
        seg[sg][t & 31] = v;
    }
    __syncthreads();
    if (t < 32) {
        float v = 0.f;
        #pragma unroll
        for (int sg = 0; sg < 8; ++sg) v += seg[sg][t];
        rep[((size_t)(b * AA + a_rep)) * HH + hq * 32 + t] = v;
    }
}

extern "C" void kernel_launch(void* const* d_in, const int* in_sizes, int n_in,
                              void* d_out, int out_size, void* d_ws, size_t ws_size,
                              hipStream_t stream) {
    const float* doc   = (const float*)d_in[0];   // [32][2048][128]
    const int*   mask  = (const int*)d_in[1];     // [32][2048]
    const float* embed = (const float*)d_in[2];   // [8][384]
    const float* proj  = (const float*)d_in[3];   // [8][128][128]

    float* out  = (float*)d_out;
    float* attn = out;                             // [32][8][2048]
    float* rep  = out + (size_t)BB * AA * SS;      // [32][8][128]

    uint4* bfrag = (uint4*)d_ws;                   // 12288 B of the 16 KB slot
    float* E     = (float*)d_ws + 4096;
    float* Zp    = E + (size_t)BB * AA * SS;
    float* pools = Zp + (size_t)BB * AA * 32;

    prep_kernel<<<8, 128, 0, stream>>>(embed, proj, bfrag);
    tile_kernel<<<dim3(32, 32), 256, 0, stream>>>(doc, mask, bfrag, E, Zp, pools);
    finalize_kernel<<<dim3(32, 32), 256, 0, stream>>>(E, Zp, pools, proj, attn, rep);
}